// Round 1
// baseline (480.277 us; speedup 1.0000x reference)
//
#include <hip/hip_runtime.h>
#include <hip/hip_bf16.h>
#include <math.h>

#define BB 8
#define AA 65536
#define CC 80
#define GG 16
#define KK 50
#define ACA (AA*CC)        // 5242880
#define NBG (BB*GG)        // 128
#define CAP 1024
#define NCHUNK 8
#define CHUNK (AA/NCHUNK)  // 8192

// ws layout (bytes)
#define OFF_ACC   0              // double[2]: pos_sum, neg_sum
#define OFF_T2    16             // float[128]: max decoded-iou per (b,g) (atomicMax as uint)
#define OFF_GMASK 528            // uint[B*C]: bitmask of g's with label c
#define OFF_CNT   3088           // int[128]: candidate counters
#define OFF_HIST  3600           // uint[128*256]: mqm histogram per (b,g)
#define OFF_CANDV 134672         // float[128*CAP]
#define OFF_CANDI 658960         // int[128*CAP]
#define OFF_IOU   1183248        // float[128*A] decoded iou
#define HEAD_WORDS 33668         // (OFF_HIST + 131072)/4 : zeroed each launch

__device__ __forceinline__ float iou_c(float ax1,float ay1,float ax2,float ay2,
                                       float bx1,float by1,float bx2,float by2){
    float lx=fmaxf(ax1,bx1), ly=fmaxf(ay1,by1);
    float rx=fminf(ax2,bx2), ry=fminf(ay2,by2);
    float w=fmaxf(rx-lx,0.f), h=fmaxf(ry-ly,0.f);
    float inter=w*h;
    float aA=(ax2-ax1)*(ay2-ay1);
    float aB=(bx2-bx1)*(by2-by1);
    return inter/(aA+aB-inter);
}

__global__ void k_init(unsigned* __restrict__ w){
    for (unsigned i=blockIdx.x*256u+threadIdx.x; i<HEAD_WORDS; i+=64u*256u) w[i]=0u;
}

__global__ void k_lut(const int* __restrict__ labels, unsigned* __restrict__ gmask){
    int b=threadIdx.x;
    if (b<BB){
        for (int g=0; g<GG; ++g){
            int c=labels[b*GG+g];
            gmask[b*CC+c] |= (1u<<g);
        }
    }
}

// sweep 1: decoded iou (store + max -> t2), mqm histogram
__global__ __launch_bounds__(256) void k_iou(const float4* __restrict__ anc4,
        const float4* __restrict__ reg4, const float4* __restrict__ tgt4,
        float* __restrict__ ioubuf, unsigned* __restrict__ t2u,
        unsigned* __restrict__ ghist){
    __shared__ unsigned hist[256];
    __shared__ float wmaxs[4];
    int tid=threadIdx.x;
    int chunk=blockIdx.x, g=blockIdx.y, b=blockIdx.z;
    int bg=b*GG+g;
    float4 tb=tgt4[bg];
    hist[tid]=0u;
    __syncthreads();
    float mx=0.f;
    int abase=chunk*CHUNK+tid;
    #pragma unroll 4
    for (int it=0; it<CHUNK/256; ++it){
        int a=abase+it*256;
        float4 an=anc4[a];
        float4 br=reg4[b*AA+a];
        float dcx=an.x+br.x*0.1f*an.z;
        float dcy=an.y+br.y*0.1f*an.w;
        float dw=an.z*__expf(br.z*0.2f);
        float dh=an.w*__expf(br.w*0.2f);
        float iou=iou_c(tb.x,tb.y,tb.z,tb.w,
                        dcx-dw*0.5f,dcy-dh*0.5f,dcx+dw*0.5f,dcy+dh*0.5f);
        ioubuf[bg*AA+a]=iou;
        mx=fmaxf(mx,iou);
        float m=iou_c(tb.x,tb.y,tb.z,tb.w,
                      an.x-an.z*0.5f,an.y-an.w*0.5f,an.x+an.z*0.5f,an.y+an.w*0.5f);
        int bin=min(255,(int)(m*256.f));
        atomicAdd(&hist[bin],1u);
    }
    for (int off=32; off; off>>=1) mx=fmaxf(mx,__shfl_down(mx,off));
    if ((tid&63)==0) wmaxs[tid>>6]=mx;
    __syncthreads();
    if (tid==0){
        float m2=fmaxf(fmaxf(wmaxs[0],wmaxs[1]),fmaxf(wmaxs[2],wmaxs[3]));
        atomicMax(&t2u[bg],__float_as_uint(m2));   // iou >= 0: uint order == float order
    }
    atomicAdd(&ghist[bg*256+tid],hist[tid]);
}

// sweep 2: threshold bin from histogram, collect candidates
__global__ __launch_bounds__(256) void k_cand(const float4* __restrict__ anc4,
        const float4* __restrict__ tgt4, const unsigned* __restrict__ ghist,
        int* __restrict__ gcnt, float* __restrict__ candv, int* __restrict__ candi){
    __shared__ unsigned h[256];
    __shared__ int sbstar;
    int tid=threadIdx.x;
    int chunk=blockIdx.x, g=blockIdx.y, b=blockIdx.z;
    int bg=b*GG+g;
    float4 tb=tgt4[bg];
    h[tid]=ghist[bg*256+tid];
    __syncthreads();
    if (tid==0){
        unsigned cum=0; int bs=0;
        for (int bin=255; bin>=0; --bin){ cum+=h[bin]; if (cum>=KK){ bs=bin; break; } }
        sbstar=bs;
    }
    __syncthreads();
    float thr=(float)sbstar;
    int abase=chunk*CHUNK+tid;
    for (int it=0; it<CHUNK/256; ++it){
        int a=abase+it*256;
        float4 an=anc4[a];
        float m=iou_c(tb.x,tb.y,tb.z,tb.w,
                      an.x-an.z*0.5f,an.y-an.w*0.5f,an.x+an.z*0.5f,an.y+an.w*0.5f);
        if (m*256.f>=thr){
            int p=atomicAdd(&gcnt[bg],1);
            if (p<CAP){ candv[bg*CAP+p]=m; candi[bg*CAP+p]=a; }
        }
    }
}

// top-50 extraction + positive bag loss, one block per (b,g)
__global__ __launch_bounds__(256) void k_select(const float4* __restrict__ anc4,
        const float4* __restrict__ reg4, const float4* __restrict__ tgt4,
        const float* __restrict__ logits, const int* __restrict__ labels,
        const int* __restrict__ gcnt, const float* __restrict__ candv,
        const int* __restrict__ candi, double* __restrict__ acc){
    __shared__ float cv[CAP];
    __shared__ int ci[CAP];
    int tid=threadIdx.x;
    int bg=blockIdx.x; int b=bg>>4, g=bg&15; (void)g;
    int cnt=gcnt[bg]; if (cnt>CAP) cnt=CAP;
    for (int j=tid; j<cnt; j+=256){ cv[j]=candv[bg*CAP+j]; ci[j]=candi[bg*CAP+j]; }
    __syncthreads();
    if (tid>=64) return;
    int lane=tid;
    int myA=-1;
    for (int k=0; k<KK; ++k){
        float bv=-1e30f; int bi=0x7fffffff; int bj=-1;
        for (int j=lane; j<cnt; j+=64){
            float v=cv[j]; int ii=ci[j];
            if (v>bv || (v==bv && ii<bi)){ bv=v; bi=ii; bj=j; }
        }
        for (int off=32; off; off>>=1){
            float ov=__shfl_down(bv,off); int oi=__shfl_down(bi,off); int oj=__shfl_down(bj,off);
            if (ov>bv || (ov==bv && oi<bi)){ bv=ov; bi=oi; bj=oj; }
        }
        int wj=__shfl(bj,0); int wi=__shfl(bi,0); float wv=__shfl(bv,0);
        if (wv>-1e29f){
            if (lane==(wj&63)) cv[wj]=-1e30f;   // owner lane marks; only it re-reads this slot
            if (lane==k) myA=wi;
        }
    }
    float p=0.f, u=0.f;
    if (lane<KK && myA>=0){
        float4 tb=tgt4[bg];
        int a=myA;
        float4 an=anc4[a];
        int lab=labels[bg];
        float lg=logits[((size_t)b*AA+(size_t)a)*CC+lab];
        float mcp=1.f/(1.f+expf(-lg));
        float gcx=((tb.x+tb.z)*0.5f-an.x)/(0.1f*an.z);
        float gcy=((tb.y+tb.w)*0.5f-an.y)/(0.1f*an.w);
        float gw=logf((tb.z-tb.x)/an.z)/0.2f;
        float gh=logf((tb.w-tb.y)/an.w)/0.2f;
        float4 br=reg4[b*AA+a];
        float v0=gcx-br.x, v1=gcy-br.y, v2=gw-br.z, v3=gh-br.w;
        float s=0.f;
        {float av=fabsf(v0); s+=(av<0.11f)?4.545454545454546f*v0*v0:av-0.055f;}
        {float av=fabsf(v1); s+=(av<0.11f)?4.545454545454546f*v1*v1:av-0.055f;}
        {float av=fabsf(v2); s+=(av<0.11f)?4.545454545454546f*v2*v2:av-0.055f;}
        {float av=fabsf(v3); s+=(av<0.11f)?4.545454545454546f*v3*v3:av-0.055f;}
        float mbp=expf(-(0.75f*s));
        p=mcp*mbp;
        u=1.f/fmaxf(1.f-p,1e-12f);
    }
    float su=u, sp=u*p;
    for (int off=32; off; off>>=1){ su+=__shfl_down(su,off); sp+=__shfl_down(sp,off); }
    if (lane==0) atomicAdd(&acc[0],(double)(-logf(sp/su)));
}

// negative (focal-ish) loss over all B*A*C logits
__global__ __launch_bounds__(256) void k_neg(const float4* __restrict__ lg4,
        const float* __restrict__ ioubuf, const float* __restrict__ t2f,
        const unsigned* __restrict__ gmask, double* __restrict__ acc){
    __shared__ unsigned smask[BB*CC];
    __shared__ float sinv[NBG];
    __shared__ double wsum[4];
    int tid=threadIdx.x;
    for (int j=tid; j<BB*CC; j+=256) smask[j]=gmask[j];
    if (tid<NBG){ float d=t2f[tid]-0.5f; sinv[tid]=(d>0.f)?(1.f/d):0.f; }
    __syncthreads();
    double loc=0.0;
    const unsigned n4=(unsigned)BB*AA*CC/4u;
    for (unsigned i=blockIdx.x*blockDim.x+tid; i<n4; i+=gridDim.x*blockDim.x){
        float4 v=lg4[i];
        unsigned e=i*4u;
        unsigned b=e/(unsigned)ACA;
        unsigned rem=e-b*(unsigned)ACA;
        unsigned a=rem/80u;
        unsigned c0=rem-a*80u;
        const unsigned mb=b*CC+c0;
        const unsigned gb=b*GG;
        float l[4]={v.x,v.y,v.z,v.w};
        float fs=0.f;
        #pragma unroll
        for (int k=0; k<4; ++k){
            float s=1.f/(1.f+__expf(-l[k]));
            unsigned m=smask[mb+k];
            float bp=0.f;
            while (m){
                unsigned g=(unsigned)__builtin_ctz(m); m&=m-1u;
                float io=ioubuf[(gb+g)*(unsigned)AA+a];
                float ob=(io-0.5f)*sinv[gb+g];
                bp=fmaxf(bp,fminf(fmaxf(ob,0.f),1.f));
            }
            float x=s*(1.f-bp);
            fs+=x*x*(-log1pf(-x));
        }
        loc+=(double)fs;
    }
    for (int off=32; off; off>>=1) loc+=__shfl_down(loc,off);
    if ((tid&63)==0) wsum[tid>>6]=loc;
    __syncthreads();
    if (tid==0) atomicAdd(&acc[1],wsum[0]+wsum[1]+wsum[2]+wsum[3]);
}

__global__ void k_fin(const double* __restrict__ acc, float* __restrict__ out){
    out[0]=(float)(0.5*acc[0]/128.0);     // ALPHA * sum(pos)/ (B*G)
    out[1]=(float)(0.5*acc[1]/6400.0);    // (1-ALPHA) * sum / (B*G*TOPK)
}

extern "C" void kernel_launch(void* const* d_in, const int* in_sizes, int n_in,
                              void* d_out, int out_size, void* d_ws, size_t ws_size,
                              hipStream_t stream){
    const float4* reg4=(const float4*)d_in[0];
    const float*  logits=(const float*)d_in[1];
    const float4* anc4=(const float4*)d_in[2];
    const float4* tgt4=(const float4*)d_in[3];
    const int*    labels=(const int*)d_in[4];
    char* ws=(char*)d_ws;
    double*   acc   =(double*)(ws+OFF_ACC);
    float*    t2f   =(float*)(ws+OFF_T2);
    unsigned* gmask =(unsigned*)(ws+OFF_GMASK);
    int*      gcnt  =(int*)(ws+OFF_CNT);
    unsigned* ghist =(unsigned*)(ws+OFF_HIST);
    float*    candv =(float*)(ws+OFF_CANDV);
    int*      candi =(int*)(ws+OFF_CANDI);
    float*    ioubuf=(float*)(ws+OFF_IOU);

    k_init<<<64,256,0,stream>>>((unsigned*)ws);
    k_lut<<<1,64,0,stream>>>(labels,gmask);
    k_iou<<<dim3(NCHUNK,GG,BB),256,0,stream>>>(anc4,reg4,tgt4,ioubuf,(unsigned*)t2f,ghist);
    k_cand<<<dim3(NCHUNK,GG,BB),256,0,stream>>>(anc4,tgt4,ghist,gcnt,candv,candi);
    k_select<<<NBG,256,0,stream>>>(anc4,reg4,tgt4,logits,labels,gcnt,candv,candi,acc);
    k_neg<<<4096,256,0,stream>>>((const float4*)logits,ioubuf,t2f,gmask,acc);
    k_fin<<<1,1,0,stream>>>(acc,(float*)d_out);
}

// Round 2
// 479.238 us; speedup vs baseline: 1.0022x; 1.0022x over previous
//
#include <hip/hip_runtime.h>
#include <hip/hip_bf16.h>
#include <math.h>

#define BB 8
#define AA 65536
#define CC 80
#define GG 16
#define KK 50
#define ACA (AA*CC)
#define NBG (BB*GG)
#define CAP 1024

// ws layout (bytes)
#define OFF_ACC   0              // double[2]
#define OFF_T2    16             // float[128]
#define OFF_THR   528            // float[128]
#define OFF_GMASK 1040           // uint[B*C]
#define OFF_CNT   3600           // int[128]
#define OFF_CCNT  4112           // int[1] correction-list counter
#define OFF_HIST  4128           // uint[128*256]
#define HEAD_WORDS 33800         // (4128+131072)/4
#define OFF_CANDV 135200         // float[128*CAP]
#define OFF_CANDI 659488         // int[128*CAP]
#define OFF_CLIST 1183776        // uint[B*A] worst case

__device__ __forceinline__ float iou_c(float ax1,float ay1,float ax2,float ay2,
                                       float bx1,float by1,float bx2,float by2){
    float lx=fmaxf(ax1,bx1), ly=fmaxf(ay1,by1);
    float rx=fminf(ax2,bx2), ry=fminf(ay2,by2);
    float w=fmaxf(rx-lx,0.f), h=fmaxf(ry-ly,0.f);
    float inter=w*h;
    float aA=(ax2-ax1)*(ay2-ay1);
    float aB=(bx2-bx1)*(by2-by1);
    return inter/(aA+aB-inter);
}

__global__ void k_init(unsigned* __restrict__ w){
    for (unsigned i=blockIdx.x*256u+threadIdx.x; i<HEAD_WORDS; i+=64u*256u) w[i]=0u;
}

__global__ void k_lut(const int* __restrict__ labels, unsigned* __restrict__ gmask){
    int b=threadIdx.x;
    if (b<BB){
        for (int g=0; g<GG; ++g){
            int c=labels[b*GG+g];
            gmask[b*CC+c] |= (1u<<g);
        }
    }
}

// fused g-loop: decode once per (b,a); per-g decoded-iou max (t2), mqm histogram,
// sparse correction-candidate emission (iou>0.5)
__global__ __launch_bounds__(256) void k_iou(const float4* __restrict__ anc4,
        const float4* __restrict__ reg4, const float4* __restrict__ tgt4,
        unsigned* __restrict__ t2u, unsigned* __restrict__ ghist,
        int* __restrict__ ccnt, unsigned* __restrict__ clist){
    __shared__ unsigned hist[GG][256];
    __shared__ float4 stb[GG];
    __shared__ unsigned st2[GG];
    int tid=threadIdx.x;
    int blk=blockIdx.x, b=blockIdx.y;
    for (int j=tid; j<GG*256; j+=256) ((unsigned*)hist)[j]=0u;
    if (tid<GG){ stb[tid]=tgt4[b*GG+tid]; st2[tid]=0u; }
    __syncthreads();
    float mx[GG];
    #pragma unroll
    for (int g=0; g<GG; ++g) mx[g]=0.f;
    int abase=blk*(AA/64)+tid;
    for (int it=0; it<(AA/64)/256; ++it){
        int a=abase+it*256;
        float4 an=anc4[a];
        float4 br=reg4[b*AA+a];
        float dcx=an.x+br.x*0.1f*an.z;
        float dcy=an.y+br.y*0.1f*an.w;
        float dw=an.z*__expf(br.z*0.2f);
        float dh=an.w*__expf(br.w*0.2f);
        float dx1=dcx-dw*0.5f, dy1=dcy-dh*0.5f, dx2=dcx+dw*0.5f, dy2=dcy+dh*0.5f;
        float ax1=an.x-an.z*0.5f, ay1=an.y-an.w*0.5f;
        float ax2=an.x+an.z*0.5f, ay2=an.y+an.w*0.5f;
        bool emit=false;
        #pragma unroll
        for (int g=0; g<GG; ++g){
            float4 tb=stb[g];
            float iou=iou_c(tb.x,tb.y,tb.z,tb.w,dx1,dy1,dx2,dy2);
            mx[g]=fmaxf(mx[g],iou);
            if (iou>0.5f) emit=true;
            float m=iou_c(tb.x,tb.y,tb.z,tb.w,ax1,ay1,ax2,ay2);
            int bin=min(255,(int)(m*256.f));
            atomicAdd(&hist[g][bin],1u);
        }
        if (emit){
            int p=atomicAdd(ccnt,1);
            clist[p]=((unsigned)b<<16)|(unsigned)a;   // each (b,a) visited once: no dedup needed
        }
    }
    #pragma unroll
    for (int g=0; g<GG; ++g){
        float v=mx[g];
        for (int off=32; off; off>>=1) v=fmaxf(v,__shfl_down(v,off));
        if ((tid&63)==0) atomicMax(&st2[g],__float_as_uint(v));
    }
    __syncthreads();
    if (tid<GG) atomicMax(&t2u[b*GG+tid],st2[tid]);
    __syncthreads();
    for (int j=tid; j<GG*256; j+=256){
        unsigned v=((unsigned*)hist)[j];
        if (v) atomicAdd(&ghist[b*GG*256+j],v);
    }
}

__global__ void k_thr(const unsigned* __restrict__ ghist, float* __restrict__ thr){
    int bg=blockIdx.x;
    if (threadIdx.x==0){
        const unsigned* h=&ghist[bg*256];
        unsigned cum=0; int bs=0;
        for (int bin=255; bin>=0; --bin){ cum+=h[bin]; if (cum>=KK){ bs=bin; break; } }
        thr[bg]=(float)bs;
    }
}

// collect top-k candidates above per-(b,g) histogram threshold (fused g-loop)
__global__ __launch_bounds__(256) void k_cand(const float4* __restrict__ anc4,
        const float4* __restrict__ tgt4, const float* __restrict__ thr,
        int* __restrict__ gcnt, float* __restrict__ candv, int* __restrict__ candi){
    __shared__ float4 stb[GG];
    __shared__ float sthr[GG];
    int tid=threadIdx.x, blk=blockIdx.x, b=blockIdx.y;
    if (tid<GG){ stb[tid]=tgt4[b*GG+tid]; sthr[tid]=thr[b*GG+tid]; }
    __syncthreads();
    int abase=blk*(AA/64)+tid;
    for (int it=0; it<(AA/64)/256; ++it){
        int a=abase+it*256;
        float4 an=anc4[a];
        float ax1=an.x-an.z*0.5f, ay1=an.y-an.w*0.5f;
        float ax2=an.x+an.z*0.5f, ay2=an.y+an.w*0.5f;
        #pragma unroll
        for (int g=0; g<GG; ++g){
            float4 tb=stb[g];
            float m=iou_c(tb.x,tb.y,tb.z,tb.w,ax1,ay1,ax2,ay2);
            if (m*256.f>=sthr[g]){
                int bg=b*GG+g;
                int p=atomicAdd(&gcnt[bg],1);
                if (p<CAP){ candv[bg*CAP+p]=m; candi[bg*CAP+p]=a; }
            }
        }
    }
}

// top-50 extraction + positive bag loss, one block per (b,g)  (unchanged: verified)
__global__ __launch_bounds__(256) void k_select(const float4* __restrict__ anc4,
        const float4* __restrict__ reg4, const float4* __restrict__ tgt4,
        const float* __restrict__ logits, const int* __restrict__ labels,
        const int* __restrict__ gcnt, const float* __restrict__ candv,
        const int* __restrict__ candi, double* __restrict__ acc){
    __shared__ float cv[CAP];
    __shared__ int ci[CAP];
    int tid=threadIdx.x;
    int bg=blockIdx.x; int b=bg>>4;
    int cnt=gcnt[bg]; if (cnt>CAP) cnt=CAP;
    for (int j=tid; j<cnt; j+=256){ cv[j]=candv[bg*CAP+j]; ci[j]=candi[bg*CAP+j]; }
    __syncthreads();
    if (tid>=64) return;
    int lane=tid;
    int myA=-1;
    for (int k=0; k<KK; ++k){
        float bv=-1e30f; int bi=0x7fffffff; int bj=-1;
        for (int j=lane; j<cnt; j+=64){
            float v=cv[j]; int ii=ci[j];
            if (v>bv || (v==bv && ii<bi)){ bv=v; bi=ii; bj=j; }
        }
        for (int off=32; off; off>>=1){
            float ov=__shfl_down(bv,off); int oi=__shfl_down(bi,off); int oj=__shfl_down(bj,off);
            if (ov>bv || (ov==bv && oi<bi)){ bv=ov; bi=oi; bj=oj; }
        }
        int wj=__shfl(bj,0); int wi=__shfl(bi,0); float wv=__shfl(bv,0);
        if (wv>-1e29f){
            if (lane==(wj&63)) cv[wj]=-1e30f;
            if (lane==k) myA=wi;
        }
    }
    float p=0.f, u=0.f;
    if (lane<KK && myA>=0){
        float4 tb=tgt4[bg];
        int a=myA;
        float4 an=anc4[a];
        int lab=labels[bg];
        float lg=logits[((size_t)b*AA+(size_t)a)*CC+lab];
        float mcp=1.f/(1.f+expf(-lg));
        float gcx=((tb.x+tb.z)*0.5f-an.x)/(0.1f*an.z);
        float gcy=((tb.y+tb.w)*0.5f-an.y)/(0.1f*an.w);
        float gw=logf((tb.z-tb.x)/an.z)/0.2f;
        float gh=logf((tb.w-tb.y)/an.w)/0.2f;
        float4 br=reg4[b*AA+a];
        float v0=gcx-br.x, v1=gcy-br.y, v2=gw-br.z, v3=gh-br.w;
        float s=0.f;
        {float av=fabsf(v0); s+=(av<0.11f)?4.545454545454546f*v0*v0:av-0.055f;}
        {float av=fabsf(v1); s+=(av<0.11f)?4.545454545454546f*v1*v1:av-0.055f;}
        {float av=fabsf(v2); s+=(av<0.11f)?4.545454545454546f*v2*v2:av-0.055f;}
        {float av=fabsf(v3); s+=(av<0.11f)?4.545454545454546f*v3*v3:av-0.055f;}
        float mbp=expf(-(0.75f*s));
        p=mcp*mbp;
        u=1.f/fmaxf(1.f-p,1e-12f);
    }
    float su=u, sp=u*p;
    for (int off=32; off; off>>=1){ su+=__shfl_down(su,off); sp+=__shfl_down(sp,off); }
    if (lane==0) atomicAdd(&acc[0],(double)(-logf(sp/su)));
}

// pure streaming base term: sum s^2 * softplus(l) over all logits (bp==0 path)
__global__ __launch_bounds__(256) void k_neg(const float4* __restrict__ lg4,
        double* __restrict__ acc){
    __shared__ double wsum[4];
    int tid=threadIdx.x;
    double loc=0.0;
    const unsigned n4=(unsigned)BB*AA*CC/4u;
    for (unsigned i=blockIdx.x*blockDim.x+tid; i<n4; i+=gridDim.x*blockDim.x){
        float4 v=lg4[i];
        float l[4]={v.x,v.y,v.z,v.w};
        float fs=0.f;
        #pragma unroll
        for (int k=0; k<4; ++k){
            float e=__expf(l[k]);
            float s=e*__builtin_amdgcn_rcpf(1.f+e);
            fs+=s*s*__logf(1.f+e);
        }
        loc+=(double)fs;
    }
    for (int off=32; off; off>>=1) loc+=__shfl_down(loc,off);
    if ((tid&63)==0) wsum[tid>>6]=loc;
    __syncthreads();
    if (tid==0) atomicAdd(&acc[1],wsum[0]+wsum[1]+wsum[2]+wsum[3]);
}

// sparse correction: anchors with some decoded-iou > 0.5 get bp>0 on the
// classes present in labels[b]; add f(s*(1-bp)) - f(s) for those (b,a,c)
__global__ __launch_bounds__(256) void k_corr(const float4* __restrict__ anc4,
        const float4* __restrict__ reg4, const float4* __restrict__ tgt4,
        const float* __restrict__ logits, const unsigned* __restrict__ gmask,
        const float* __restrict__ t2f, const int* __restrict__ ccnt,
        const unsigned* __restrict__ clist, double* __restrict__ acc){
    __shared__ double wsum[4];
    int tid=threadIdx.x;
    int n=*ccnt;
    double loc=0.0;
    for (int i=blockIdx.x*blockDim.x+tid; i<n; i+=gridDim.x*blockDim.x){
        unsigned key=clist[i];
        int b=key>>16, a=key&0xffff;
        float4 an=anc4[a];
        float4 br=reg4[b*AA+a];
        float dcx=an.x+br.x*0.1f*an.z;
        float dcy=an.y+br.y*0.1f*an.w;
        float dw=an.z*__expf(br.z*0.2f);
        float dh=an.w*__expf(br.w*0.2f);
        float dx1=dcx-dw*0.5f, dy1=dcy-dh*0.5f, dx2=dcx+dw*0.5f, dy2=dcy+dh*0.5f;
        float obp[GG];
        #pragma unroll
        for (int g=0; g<GG; ++g){
            float4 tb=tgt4[b*GG+g];
            float iou=iou_c(tb.x,tb.y,tb.z,tb.w,dx1,dy1,dx2,dy2);
            float d=t2f[b*GG+g]-0.5f;
            float inv=(d>0.f)?1.f/d:0.f;
            obp[g]=fminf(fmaxf((iou-0.5f)*inv,0.f),1.f);
        }
        for (int c=0; c<CC; ++c){
            unsigned m=gmask[b*CC+c];
            if (!m) continue;
            float bp=0.f;
            while (m){ unsigned g=(unsigned)__builtin_ctz(m); m&=m-1u; bp=fmaxf(bp,obp[g]); }
            if (bp<=0.f) continue;
            float lg=logits[((size_t)b*AA+(size_t)a)*CC+c];
            float e=__expf(lg);
            float s=e*__builtin_amdgcn_rcpf(1.f+e);
            float x=s*(1.f-bp);
            float fx=x*x*(-__logf(fmaxf(1.f-x,1e-12f)));
            float fs=s*s*__logf(1.f+e);
            loc+=(double)(fx-fs);
        }
    }
    for (int off=32; off; off>>=1) loc+=__shfl_down(loc,off);
    if ((tid&63)==0) wsum[tid>>6]=loc;
    __syncthreads();
    if (tid==0) atomicAdd(&acc[1],wsum[0]+wsum[1]+wsum[2]+wsum[3]);
}

__global__ void k_fin(const double* __restrict__ acc, float* __restrict__ out){
    out[0]=(float)(0.5*acc[0]/128.0);
    out[1]=(float)(0.5*acc[1]/6400.0);
}

extern "C" void kernel_launch(void* const* d_in, const int* in_sizes, int n_in,
                              void* d_out, int out_size, void* d_ws, size_t ws_size,
                              hipStream_t stream){
    const float4* reg4=(const float4*)d_in[0];
    const float*  logits=(const float*)d_in[1];
    const float4* anc4=(const float4*)d_in[2];
    const float4* tgt4=(const float4*)d_in[3];
    const int*    labels=(const int*)d_in[4];
    char* ws=(char*)d_ws;
    double*   acc   =(double*)(ws+OFF_ACC);
    float*    t2f   =(float*)(ws+OFF_T2);
    float*    thr   =(float*)(ws+OFF_THR);
    unsigned* gmask =(unsigned*)(ws+OFF_GMASK);
    int*      gcnt  =(int*)(ws+OFF_CNT);
    int*      ccnt  =(int*)(ws+OFF_CCNT);
    unsigned* ghist =(unsigned*)(ws+OFF_HIST);
    float*    candv =(float*)(ws+OFF_CANDV);
    int*      candi =(int*)(ws+OFF_CANDI);
    unsigned* clist =(unsigned*)(ws+OFF_CLIST);

    k_init<<<64,256,0,stream>>>((unsigned*)ws);
    k_lut<<<1,64,0,stream>>>(labels,gmask);
    k_iou<<<dim3(64,BB),256,0,stream>>>(anc4,reg4,tgt4,(unsigned*)t2f,ghist,ccnt,clist);
    k_thr<<<NBG,64,0,stream>>>(ghist,thr);
    k_cand<<<dim3(64,BB),256,0,stream>>>(anc4,tgt4,thr,gcnt,candv,candi);
    k_select<<<NBG,256,0,stream>>>(anc4,reg4,tgt4,logits,labels,gcnt,candv,candi,acc);
    k_neg<<<4096,256,0,stream>>>((const float4*)logits,acc);
    k_corr<<<256,256,0,stream>>>(anc4,reg4,tgt4,logits,gmask,t2f,ccnt,clist,acc);
    k_fin<<<1,1,0,stream>>>(acc,(float*)d_out);
}

// Round 3
// 474.125 us; speedup vs baseline: 1.0130x; 1.0108x over previous
//
#include <hip/hip_runtime.h>
#include <hip/hip_bf16.h>
#include <math.h>

#define BB 8
#define AA 65536
#define CC 80
#define GG 16
#define KK 50
#define ACA (AA*CC)
#define NBG (BB*GG)
#define CAP 1024
#define NCH 128
#define CHUNK (AA/NCH)   // 512

// ws layout (bytes)
#define OFF_ACC   0              // double[2]
#define OFF_T2    16             // float[128]
#define OFF_THR   528            // float[128]
#define OFF_GMASK 1040           // uint[B*C]
#define OFF_CNT   3600           // int[128]
#define OFF_CCNT  4112           // int[1] correction-list counter
#define OFF_HIST  4128           // uint[128*256]
#define HEAD_WORDS 33800         // (4128+131072)/4
#define OFF_CANDV 135200         // float[128*CAP]
#define OFF_CANDI 659488         // int[128*CAP]
#define OFF_CLIST 1183776        // uint list

__device__ __forceinline__ float iou_c(float ax1,float ay1,float ax2,float ay2,
                                       float bx1,float by1,float bx2,float by2){
    float lx=fmaxf(ax1,bx1), ly=fmaxf(ay1,by1);
    float rx=fminf(ax2,bx2), ry=fminf(ay2,by2);
    float w=fmaxf(rx-lx,0.f), h=fmaxf(ry-ly,0.f);
    float inter=w*h;
    float aA=(ax2-ax1)*(ay2-ay1);
    float aB=(bx2-bx1)*(by2-by1);
    return inter/(aA+aB-inter);
}

__global__ void k_init(unsigned* __restrict__ w){
    for (unsigned i=blockIdx.x*256u+threadIdx.x; i<HEAD_WORDS; i+=64u*256u) w[i]=0u;
}

__global__ void k_lut(const int* __restrict__ labels, unsigned* __restrict__ gmask){
    int b=threadIdx.x;
    if (b<BB){
        for (int g=0; g<GG; ++g){
            int c=labels[b*GG+g];
            gmask[b*CC+c] |= (1u<<g);
        }
    }
}

// fused g-loop: decode once per (b,a); per-g decoded-iou max (t2), mqm histogram
// (m>0 only: bin-0 same-address atomic hot-spot eliminated), correction emission
__global__ __launch_bounds__(256) void k_iou(const float4* __restrict__ anc4,
        const float4* __restrict__ reg4, const float4* __restrict__ tgt4,
        unsigned* __restrict__ t2u, unsigned* __restrict__ ghist,
        int* __restrict__ ccnt, unsigned* __restrict__ clist){
    __shared__ unsigned hist[GG][256];
    __shared__ float4 stb[GG];
    __shared__ unsigned st2[GG];
    int tid=threadIdx.x;
    int blk=blockIdx.x, b=blockIdx.y;
    for (int j=tid; j<GG*256; j+=256) ((unsigned*)hist)[j]=0u;
    if (tid<GG){ stb[tid]=tgt4[b*GG+tid]; st2[tid]=0u; }
    __syncthreads();
    float mx[GG];
    #pragma unroll
    for (int g=0; g<GG; ++g) mx[g]=0.f;
    int abase=blk*CHUNK+tid;
    for (int it=0; it<CHUNK/256; ++it){
        int a=abase+it*256;
        float4 an=anc4[a];
        float4 br=reg4[b*AA+a];
        float dcx=an.x+br.x*0.1f*an.z;
        float dcy=an.y+br.y*0.1f*an.w;
        float dw=an.z*__expf(br.z*0.2f);
        float dh=an.w*__expf(br.w*0.2f);
        float dx1=dcx-dw*0.5f, dy1=dcy-dh*0.5f, dx2=dcx+dw*0.5f, dy2=dcy+dh*0.5f;
        float ax1=an.x-an.z*0.5f, ay1=an.y-an.w*0.5f;
        float ax2=an.x+an.z*0.5f, ay2=an.y+an.w*0.5f;
        bool emit=false;
        #pragma unroll
        for (int g=0; g<GG; ++g){
            float4 tb=stb[g];
            float iou=iou_c(tb.x,tb.y,tb.z,tb.w,dx1,dy1,dx2,dy2);
            mx[g]=fmaxf(mx[g],iou);
            if (iou>0.5f) emit=true;
            float m=iou_c(tb.x,tb.y,tb.z,tb.w,ax1,ay1,ax2,ay2);
            if (m>0.f){
                int bin=min(255,(int)(m*256.f));
                atomicAdd(&hist[g][bin],1u);
            }
        }
        if (emit){
            int p=atomicAdd(ccnt,1);
            clist[p]=((unsigned)b<<16)|(unsigned)a;
        }
    }
    #pragma unroll
    for (int g=0; g<GG; ++g){
        float v=mx[g];
        for (int off=32; off; off>>=1) v=fmaxf(v,__shfl_down(v,off));
        if ((tid&63)==0) atomicMax(&st2[g],__float_as_uint(v));
    }
    __syncthreads();
    if (tid<GG) atomicMax(&t2u[b*GG+tid],st2[tid]);
    __syncthreads();
    for (int j=tid; j<GG*256; j+=256){
        unsigned v=((unsigned*)hist)[j];
        if (v) atomicAdd(&ghist[b*GG*256+j],v);
    }
}

__global__ void k_thr(const unsigned* __restrict__ ghist, float* __restrict__ thr){
    int bg=blockIdx.x;
    if (threadIdx.x==0){
        const unsigned* h=&ghist[bg*256];
        unsigned cum=0; int bs=0;
        for (int bin=255; bin>=0; --bin){ cum+=h[bin]; if (cum>=KK){ bs=bin; break; } }
        thr[bg]=(float)bs;
    }
}

// collect candidates above per-(b,g) histogram threshold
__global__ __launch_bounds__(256) void k_cand(const float4* __restrict__ anc4,
        const float4* __restrict__ tgt4, const float* __restrict__ thr,
        int* __restrict__ gcnt, float* __restrict__ candv, int* __restrict__ candi){
    __shared__ float4 stb[GG];
    __shared__ float sthr[GG];
    int tid=threadIdx.x, blk=blockIdx.x, b=blockIdx.y;
    if (tid<GG){ stb[tid]=tgt4[b*GG+tid]; sthr[tid]=thr[b*GG+tid]; }
    __syncthreads();
    int abase=blk*CHUNK+tid;
    for (int it=0; it<CHUNK/256; ++it){
        int a=abase+it*256;
        float4 an=anc4[a];
        float ax1=an.x-an.z*0.5f, ay1=an.y-an.w*0.5f;
        float ax2=an.x+an.z*0.5f, ay2=an.y+an.w*0.5f;
        #pragma unroll
        for (int g=0; g<GG; ++g){
            float4 tb=stb[g];
            float m=iou_c(tb.x,tb.y,tb.z,tb.w,ax1,ay1,ax2,ay2);
            if (m>0.f && m*256.f>=sthr[g]){
                int bg=b*GG+g;
                int p=atomicAdd(&gcnt[bg],1);
                if (p<CAP){ candv[bg*CAP+p]=m; candi[bg*CAP+p]=a; }
            }
        }
    }
}

// top-50 extraction + positive bag loss, one wave per (b,g)
__global__ __launch_bounds__(64) void k_select(const float4* __restrict__ anc4,
        const float4* __restrict__ reg4, const float4* __restrict__ tgt4,
        const float* __restrict__ logits, const int* __restrict__ labels,
        const int* __restrict__ gcnt, const float* __restrict__ candv,
        const int* __restrict__ candi, double* __restrict__ acc){
    __shared__ float cv[CAP];
    __shared__ int ci[CAP];
    int lane=threadIdx.x;
    int bg=blockIdx.x; int b=bg>>4;
    int cnt=gcnt[bg]; if (cnt>CAP) cnt=CAP;
    for (int j=lane; j<cnt; j+=64){ cv[j]=candv[bg*CAP+j]; ci[j]=candi[bg*CAP+j]; }
    __syncthreads();
    int myA=-1;
    for (int k=0; k<KK; ++k){
        float bv=-1e30f; int bi=0x7fffffff; int bj=-1;
        for (int j=lane; j<cnt; j+=64){
            float v=cv[j]; int ii=ci[j];
            if (v>bv || (v==bv && ii<bi)){ bv=v; bi=ii; bj=j; }
        }
        for (int off=32; off; off>>=1){
            float ov=__shfl_down(bv,off); int oi=__shfl_down(bi,off); int oj=__shfl_down(bj,off);
            if (ov>bv || (ov==bv && oi<bi)){ bv=ov; bi=oi; bj=oj; }
        }
        int wj=__shfl(bj,0); int wi=__shfl(bi,0); float wv=__shfl(bv,0);
        if (wv>-1e29f){
            if (lane==(wj&63)) cv[wj]=-1e30f;
            if (lane==k) myA=wi;
        }
    }
    float p=0.f, u=0.f;
    if (lane<KK && myA>=0){
        float4 tb=tgt4[bg];
        int a=myA;
        float4 an=anc4[a];
        int lab=labels[bg];
        float lg=logits[((size_t)b*AA+(size_t)a)*CC+lab];
        float mcp=1.f/(1.f+expf(-lg));
        float gcx=((tb.x+tb.z)*0.5f-an.x)/(0.1f*an.z);
        float gcy=((tb.y+tb.w)*0.5f-an.y)/(0.1f*an.w);
        float gw=logf((tb.z-tb.x)/an.z)/0.2f;
        float gh=logf((tb.w-tb.y)/an.w)/0.2f;
        float4 br=reg4[b*AA+a];
        float v0=gcx-br.x, v1=gcy-br.y, v2=gw-br.z, v3=gh-br.w;
        float s=0.f;
        {float av=fabsf(v0); s+=(av<0.11f)?4.545454545454546f*v0*v0:av-0.055f;}
        {float av=fabsf(v1); s+=(av<0.11f)?4.545454545454546f*v1*v1:av-0.055f;}
        {float av=fabsf(v2); s+=(av<0.11f)?4.545454545454546f*v2*v2:av-0.055f;}
        {float av=fabsf(v3); s+=(av<0.11f)?4.545454545454546f*v3*v3:av-0.055f;}
        float mbp=expf(-(0.75f*s));
        p=mcp*mbp;
        u=1.f/fmaxf(1.f-p,1e-12f);
    }
    float su=u, sp=u*p;
    for (int off=32; off; off>>=1){ su+=__shfl_down(su,off); sp+=__shfl_down(sp,off); }
    if (lane==0) atomicAdd(&acc[0],(double)(-logf(sp/su)));
}

// streaming base term: sum s^2 * softplus(l) over all logits
__global__ __launch_bounds__(256) void k_neg(const float4* __restrict__ lg4,
        double* __restrict__ acc){
    __shared__ double wsum[4];
    int tid=threadIdx.x;
    double loc=0.0;
    const unsigned n4=(unsigned)BB*AA*CC/4u;
    for (unsigned i=blockIdx.x*blockDim.x+tid; i<n4; i+=gridDim.x*blockDim.x){
        float4 v=lg4[i];
        float l[4]={v.x,v.y,v.z,v.w};
        float fs=0.f;
        #pragma unroll
        for (int k=0; k<4; ++k){
            float e=__expf(l[k]);
            float s=e*__builtin_amdgcn_rcpf(1.f+e);
            fs+=s*s*__logf(1.f+e);
        }
        loc+=(double)fs;
    }
    for (int off=32; off; off>>=1) loc+=__shfl_down(loc,off);
    if ((tid&63)==0) wsum[tid>>6]=loc;
    __syncthreads();
    if (tid==0) atomicAdd(&acc[1],wsum[0]+wsum[1]+wsum[2]+wsum[3]);
}

// sparse correction for anchors with some decoded-iou > 0.5
__global__ __launch_bounds__(256) void k_corr(const float4* __restrict__ anc4,
        const float4* __restrict__ reg4, const float4* __restrict__ tgt4,
        const float* __restrict__ logits, const unsigned* __restrict__ gmask,
        const float* __restrict__ t2f, const int* __restrict__ ccnt,
        const unsigned* __restrict__ clist, double* __restrict__ acc){
    __shared__ double wsum[4];
    int tid=threadIdx.x;
    int n=*ccnt;
    double loc=0.0;
    for (int i=blockIdx.x*blockDim.x+tid; i<n; i+=gridDim.x*blockDim.x){
        unsigned key=clist[i];
        int b=key>>16, a=key&0xffff;
        float4 an=anc4[a];
        float4 br=reg4[b*AA+a];
        float dcx=an.x+br.x*0.1f*an.z;
        float dcy=an.y+br.y*0.1f*an.w;
        float dw=an.z*__expf(br.z*0.2f);
        float dh=an.w*__expf(br.w*0.2f);
        float dx1=dcx-dw*0.5f, dy1=dcy-dh*0.5f, dx2=dcx+dw*0.5f, dy2=dcy+dh*0.5f;
        float obp[GG];
        #pragma unroll
        for (int g=0; g<GG; ++g){
            float4 tb=tgt4[b*GG+g];
            float iou=iou_c(tb.x,tb.y,tb.z,tb.w,dx1,dy1,dx2,dy2);
            float d=t2f[b*GG+g]-0.5f;
            float inv=(d>0.f)?1.f/d:0.f;
            obp[g]=fminf(fmaxf((iou-0.5f)*inv,0.f),1.f);
        }
        for (int c=0; c<CC; ++c){
            unsigned m=gmask[b*CC+c];
            if (!m) continue;
            float bp=0.f;
            while (m){ unsigned g=(unsigned)__builtin_ctz(m); m&=m-1u; bp=fmaxf(bp,obp[g]); }
            if (bp<=0.f) continue;
            float lg=logits[((size_t)b*AA+(size_t)a)*CC+c];
            float e=__expf(lg);
            float s=e*__builtin_amdgcn_rcpf(1.f+e);
            float x=s*(1.f-bp);
            float fx=x*x*(-__logf(fmaxf(1.f-x,1e-12f)));
            float fs=s*s*__logf(1.f+e);
            loc+=(double)(fx-fs);
        }
    }
    for (int off=32; off; off>>=1) loc+=__shfl_down(loc,off);
    if ((tid&63)==0) wsum[tid>>6]=loc;
    __syncthreads();
    if (tid==0) atomicAdd(&acc[1],wsum[0]+wsum[1]+wsum[2]+wsum[3]);
}

__global__ void k_fin(const double* __restrict__ acc, float* __restrict__ out){
    out[0]=(float)(0.5*acc[0]/128.0);
    out[1]=(float)(0.5*acc[1]/6400.0);
}

extern "C" void kernel_launch(void* const* d_in, const int* in_sizes, int n_in,
                              void* d_out, int out_size, void* d_ws, size_t ws_size,
                              hipStream_t stream){
    const float4* reg4=(const float4*)d_in[0];
    const float*  logits=(const float*)d_in[1];
    const float4* anc4=(const float4*)d_in[2];
    const float4* tgt4=(const float4*)d_in[3];
    const int*    labels=(const int*)d_in[4];
    char* ws=(char*)d_ws;
    double*   acc   =(double*)(ws+OFF_ACC);
    float*    t2f   =(float*)(ws+OFF_T2);
    float*    thr   =(float*)(ws+OFF_THR);
    unsigned* gmask =(unsigned*)(ws+OFF_GMASK);
    int*      gcnt  =(int*)(ws+OFF_CNT);
    int*      ccnt  =(int*)(ws+OFF_CCNT);
    unsigned* ghist =(unsigned*)(ws+OFF_HIST);
    float*    candv =(float*)(ws+OFF_CANDV);
    int*      candi =(int*)(ws+OFF_CANDI);
    unsigned* clist =(unsigned*)(ws+OFF_CLIST);

    k_init<<<64,256,0,stream>>>((unsigned*)ws);
    k_lut<<<1,64,0,stream>>>(labels,gmask);
    k_iou<<<dim3(NCH,BB),256,0,stream>>>(anc4,reg4,tgt4,(unsigned*)t2f,ghist,ccnt,clist);
    k_thr<<<NBG,64,0,stream>>>(ghist,thr);
    k_cand<<<dim3(NCH,BB),256,0,stream>>>(anc4,tgt4,thr,gcnt,candv,candi);
    k_select<<<NBG,64,0,stream>>>(anc4,reg4,tgt4,logits,labels,gcnt,candv,candi,acc);
    k_neg<<<4096,256,0,stream>>>((const float4*)logits,acc);
    k_corr<<<256,256,0,stream>>>(anc4,reg4,tgt4,logits,gmask,t2f,ccnt,clist,acc);
    k_fin<<<1,1,0,stream>>>(acc,(float*)d_out);
}

// Round 5
// 403.694 us; speedup vs baseline: 1.1897x; 1.1745x over previous
//
#include <hip/hip_runtime.h>
#include <hip/hip_bf16.h>
#include <math.h>

#define BB 8
#define AA 65536
#define CC 80
#define GG 16
#define KK 50
#define NBG (BB*GG)
#define CAP 2048
#define BINS 64
#define NCH 128
#define CHUNK (AA/NCH)   // 512

// ws layout (bytes)
#define OFF_ACC   0              // double[2]
#define OFF_T2    16             // float[128]
#define OFF_THR   528            // float[128]
#define OFF_GMASK 1040           // uint[B*C]
#define OFF_CNT   3600           // int[128]
#define OFF_CCNT  4112           // int[1]
#define OFF_HIST  4128           // uint[128*64]
#define HEAD_WORDS 9224          // (4128+32768)/4
#define OFF_CANDV 36896          // float[128*CAP]
#define OFF_CANDI 1085472        // int[128*CAP]
#define OFF_CLIST 2134048        // uint list

__device__ __forceinline__ float iou_c(float ax1,float ay1,float ax2,float ay2,
                                       float bx1,float by1,float bx2,float by2){
    float lx=fmaxf(ax1,bx1), ly=fmaxf(ay1,by1);
    float rx=fminf(ax2,bx2), ry=fminf(ay2,by2);
    float w=fmaxf(rx-lx,0.f), h=fmaxf(ry-ly,0.f);
    float inter=w*h;
    float aA=(ax2-ax1)*(ay2-ay1);
    float aB=(bx2-bx1)*(by2-by1);
    return inter/(aA+aB-inter);
}

__global__ void k_init(unsigned* __restrict__ w){
    for (unsigned i=blockIdx.x*256u+threadIdx.x; i<HEAD_WORDS; i+=64u*256u) w[i]=0u;
}

__global__ void k_lut(const int* __restrict__ labels, unsigned* __restrict__ gmask){
    int i=threadIdx.x;
    if (i<NBG){
        int b=i>>4; int c=labels[i];
        atomicOr(&gmask[b*CC+c], 1u<<(i&15));
    }
}

// fused g-loop: decode once per (b,a); per-g decoded-iou max (t2), 64-bin mqm
// histogram (m>0 only), block-aggregated correction emission (1 ccnt atomic/block)
__global__ __launch_bounds__(256) void k_iou(const float4* __restrict__ anc4,
        const float4* __restrict__ reg4, const float4* __restrict__ tgt4,
        unsigned* __restrict__ t2u, unsigned* __restrict__ ghist,
        int* __restrict__ ccnt, unsigned* __restrict__ clist){
    __shared__ unsigned hist[GG][BINS];
    __shared__ float4 stb[GG];
    __shared__ unsigned st2[GG];
    __shared__ unsigned lbuf[CHUNK];
    __shared__ int lcnt;
    __shared__ int lbase;
    int tid=threadIdx.x;
    int blk=blockIdx.x, b=blockIdx.y;
    for (int j=tid; j<GG*BINS; j+=256) ((unsigned*)hist)[j]=0u;
    if (tid<GG){ stb[tid]=tgt4[b*GG+tid]; st2[tid]=0u; }
    if (tid==0) lcnt=0;
    __syncthreads();
    float mx[GG];
    #pragma unroll
    for (int g=0; g<GG; ++g) mx[g]=0.f;
    int abase=blk*CHUNK+tid;
    for (int it=0; it<CHUNK/256; ++it){
        int a=abase+it*256;
        float4 an=anc4[a];
        float4 br=reg4[b*AA+a];
        float dcx=an.x+br.x*0.1f*an.z;
        float dcy=an.y+br.y*0.1f*an.w;
        float dw=an.z*__expf(br.z*0.2f);
        float dh=an.w*__expf(br.w*0.2f);
        float dx1=dcx-dw*0.5f, dy1=dcy-dh*0.5f, dx2=dcx+dw*0.5f, dy2=dcy+dh*0.5f;
        float ax1=an.x-an.z*0.5f, ay1=an.y-an.w*0.5f;
        float ax2=an.x+an.z*0.5f, ay2=an.y+an.w*0.5f;
        bool emit=false;
        #pragma unroll
        for (int g=0; g<GG; ++g){
            float4 tb=stb[g];
            float iou=iou_c(tb.x,tb.y,tb.z,tb.w,dx1,dy1,dx2,dy2);
            mx[g]=fmaxf(mx[g],iou);
            if (iou>0.5f) emit=true;
            float m=iou_c(tb.x,tb.y,tb.z,tb.w,ax1,ay1,ax2,ay2);
            if (m>0.f){
                int bin=min(BINS-1,(int)(m*(float)BINS));
                atomicAdd(&hist[g][bin],1u);
            }
        }
        if (emit){
            int p=atomicAdd(&lcnt,1);
            lbuf[p]=(unsigned)a;
        }
    }
    #pragma unroll
    for (int g=0; g<GG; ++g){
        float v=mx[g];
        for (int off=32; off; off>>=1) v=fmaxf(v,__shfl_down(v,off));
        if ((tid&63)==0) atomicMax(&st2[g],__float_as_uint(v));
    }
    __syncthreads();
    if (tid<GG) atomicMax(&t2u[b*GG+tid],st2[tid]);
    if (tid==0 && lcnt>0) lbase=atomicAdd(ccnt,lcnt);
    __syncthreads();
    for (int j=tid; j<GG*BINS; j+=256){
        unsigned v=((unsigned*)hist)[j];
        if (v) atomicAdd(&ghist[b*GG*BINS+j],v);
    }
    unsigned bb=(unsigned)b<<16;
    for (int j=tid; j<lcnt; j+=256) clist[lbase+j]=bb|lbuf[j];
}

// one wave per (b,g): suffix-scan 64 bins, highest bin with cum>=KK
__global__ __launch_bounds__(64) void k_thr(const unsigned* __restrict__ ghist,
        float* __restrict__ thr){
    int bg=blockIdx.x, lane=threadIdx.x;
    unsigned v=ghist[bg*BINS+lane];
    #pragma unroll
    for (int off=1; off<64; off<<=1){
        unsigned o=__shfl_down(v,off);
        if (lane+off<64) v+=o;
    }
    unsigned long long mask=__ballot(v>=KK);
    int bs = mask ? (63-__clzll(mask)) : 0;
    if (lane==0) thr[bg]=(float)bs;
}

// collect candidates above threshold; wave-aggregated gcnt reservation
__global__ __launch_bounds__(256) void k_cand(const float4* __restrict__ anc4,
        const float4* __restrict__ tgt4, const float* __restrict__ thr,
        int* __restrict__ gcnt, float* __restrict__ candv, int* __restrict__ candi){
    __shared__ float4 stb[GG];
    __shared__ float sthr[GG];
    int tid=threadIdx.x, blk=blockIdx.x, b=blockIdx.y;
    int lane=tid&63;
    if (tid<GG){ stb[tid]=tgt4[b*GG+tid]; sthr[tid]=thr[b*GG+tid]; }
    __syncthreads();
    int abase=blk*CHUNK+tid;
    for (int it=0; it<CHUNK/256; ++it){
        int a=abase+it*256;
        float4 an=anc4[a];
        float ax1=an.x-an.z*0.5f, ay1=an.y-an.w*0.5f;
        float ax2=an.x+an.z*0.5f, ay2=an.y+an.w*0.5f;
        #pragma unroll
        for (int g=0; g<GG; ++g){
            float4 tb=stb[g];
            float m=iou_c(tb.x,tb.y,tb.z,tb.w,ax1,ay1,ax2,ay2);
            bool push=(m>0.f && m*(float)BINS>=sthr[g]);
            unsigned long long msk=__ballot(push);
            if (msk){
                int bg=b*GG+g;
                int n=__popcll(msk);
                int ldr=__ffsll((long long)msk)-1;
                int base=0;
                if (lane==ldr) base=atomicAdd(&gcnt[bg],n);
                base=__shfl(base,ldr);
                if (push){
                    int p=base+(int)__popcll(msk&((1ull<<lane)-1ull));
                    if (p<CAP){ candv[bg*CAP+p]=m; candi[bg*CAP+p]=a; }
                }
            }
        }
    }
}

// top-50 extraction + positive bag loss, one wave per (b,g)
__global__ __launch_bounds__(64) void k_select(const float4* __restrict__ anc4,
        const float4* __restrict__ reg4, const float4* __restrict__ tgt4,
        const float* __restrict__ logits, const int* __restrict__ labels,
        const int* __restrict__ gcnt, const float* __restrict__ candv,
        const int* __restrict__ candi, double* __restrict__ acc){
    __shared__ float cv[CAP];
    __shared__ int ci[CAP];
    int lane=threadIdx.x;
    int bg=blockIdx.x; int b=bg>>4;
    int cnt=gcnt[bg]; if (cnt>CAP) cnt=CAP;
    for (int j=lane; j<cnt; j+=64){ cv[j]=candv[bg*CAP+j]; ci[j]=candi[bg*CAP+j]; }
    __syncthreads();
    int myA=-1;
    for (int k=0; k<KK; ++k){
        float bv=-1e30f; int bi=0x7fffffff; int bj=-1;
        for (int j=lane; j<cnt; j+=64){
            float v=cv[j]; int ii=ci[j];
            if (v>bv || (v==bv && ii<bi)){ bv=v; bi=ii; bj=j; }
        }
        for (int off=32; off; off>>=1){
            float ov=__shfl_down(bv,off); int oi=__shfl_down(bi,off); int oj=__shfl_down(bj,off);
            if (ov>bv || (ov==bv && oi<bi)){ bv=ov; bi=oi; bj=oj; }
        }
        int wj=__shfl(bj,0); int wi=__shfl(bi,0); float wv=__shfl(bv,0);
        if (wv>-1e29f){
            if (lane==(wj&63)) cv[wj]=-1e30f;
            if (lane==k) myA=wi;
        }
    }
    float p=0.f, u=0.f;
    if (lane<KK && myA>=0){
        float4 tb=tgt4[bg];
        int a=myA;
        float4 an=anc4[a];
        int lab=labels[bg];
        float lg=logits[((size_t)b*AA+(size_t)a)*CC+lab];
        float mcp=1.f/(1.f+expf(-lg));
        float gcx=((tb.x+tb.z)*0.5f-an.x)/(0.1f*an.z);
        float gcy=((tb.y+tb.w)*0.5f-an.y)/(0.1f*an.w);
        float gw=logf((tb.z-tb.x)/an.z)/0.2f;
        float gh=logf((tb.w-tb.y)/an.w)/0.2f;
        float4 br=reg4[b*AA+a];
        float v0=gcx-br.x, v1=gcy-br.y, v2=gw-br.z, v3=gh-br.w;
        float s=0.f;
        {float av=fabsf(v0); s+=(av<0.11f)?4.545454545454546f*v0*v0:av-0.055f;}
        {float av=fabsf(v1); s+=(av<0.11f)?4.545454545454546f*v1*v1:av-0.055f;}
        {float av=fabsf(v2); s+=(av<0.11f)?4.545454545454546f*v2*v2:av-0.055f;}
        {float av=fabsf(v3); s+=(av<0.11f)?4.545454545454546f*v3*v3:av-0.055f;}
        float mbp=expf(-(0.75f*s));
        p=mcp*mbp;
        u=1.f/fmaxf(1.f-p,1e-12f);
    }
    float su=u, sp=u*p;
    for (int off=32; off; off>>=1){ su+=__shfl_down(su,off); sp+=__shfl_down(sp,off); }
    if (lane==0) atomicAdd(&acc[0],(double)(-logf(sp/su)));
}

// streaming base term: sum s^2 * softplus(l) over all logits
__global__ __launch_bounds__(256) void k_neg(const float4* __restrict__ lg4,
        double* __restrict__ acc){
    __shared__ double wsum[4];
    int tid=threadIdx.x;
    double loc=0.0;
    const unsigned n4=(unsigned)BB*AA*CC/4u;
    for (unsigned i=blockIdx.x*blockDim.x+tid; i<n4; i+=gridDim.x*blockDim.x){
        float4 v=lg4[i];
        float l[4]={v.x,v.y,v.z,v.w};
        float fs=0.f;
        #pragma unroll
        for (int k=0; k<4; ++k){
            float e=__expf(l[k]);
            float s=e*__builtin_amdgcn_rcpf(1.f+e);
            fs+=s*s*__logf(1.f+e);
        }
        loc+=(double)fs;
    }
    for (int off=32; off; off>>=1) loc+=__shfl_down(loc,off);
    if ((tid&63)==0) wsum[tid>>6]=loc;
    __syncthreads();
    if (tid==0) atomicAdd(&acc[1],wsum[0]+wsum[1]+wsum[2]+wsum[3]);
}

// sparse correction for anchors with some decoded-iou > 0.5
__global__ __launch_bounds__(256) void k_corr(const float4* __restrict__ anc4,
        const float4* __restrict__ reg4, const float4* __restrict__ tgt4,
        const float* __restrict__ logits, const unsigned* __restrict__ gmask,
        const float* __restrict__ t2f, const int* __restrict__ ccnt,
        const unsigned* __restrict__ clist, double* __restrict__ acc){
    __shared__ double wsum[4];
    int tid=threadIdx.x;
    int n=*ccnt;
    double loc=0.0;
    for (int i=blockIdx.x*blockDim.x+tid; i<n; i+=gridDim.x*blockDim.x){
        unsigned key=clist[i];
        int b=key>>16, a=key&0xffff;
        float4 an=anc4[a];
        float4 br=reg4[b*AA+a];
        float dcx=an.x+br.x*0.1f*an.z;
        float dcy=an.y+br.y*0.1f*an.w;
        float dw=an.z*__expf(br.z*0.2f);
        float dh=an.w*__expf(br.w*0.2f);
        float dx1=dcx-dw*0.5f, dy1=dcy-dh*0.5f, dx2=dcx+dw*0.5f, dy2=dcy+dh*0.5f;
        float obp[GG];
        #pragma unroll
        for (int g=0; g<GG; ++g){
            float4 tb=tgt4[b*GG+g];
            float iou=iou_c(tb.x,tb.y,tb.z,tb.w,dx1,dy1,dx2,dy2);
            float d=t2f[b*GG+g]-0.5f;
            float inv=(d>0.f)?1.f/d:0.f;
            obp[g]=fminf(fmaxf((iou-0.5f)*inv,0.f),1.f);
        }
        for (int c=0; c<CC; ++c){
            unsigned m=gmask[b*CC+c];
            if (!m) continue;
            float bp=0.f;
            while (m){ unsigned g=(unsigned)__builtin_ctz(m); m&=m-1u; bp=fmaxf(bp,obp[g]); }
            if (bp<=0.f) continue;
            float lg=logits[((size_t)b*AA+(size_t)a)*CC+c];
            float e=__expf(lg);
            float s=e*__builtin_amdgcn_rcpf(1.f+e);
            float x=s*(1.f-bp);
            float fx=x*x*(-__logf(fmaxf(1.f-x,1e-12f)));
            float fs=s*s*__logf(1.f+e);
            loc+=(double)(fx-fs);
        }
    }
    for (int off=32; off; off>>=1) loc+=__shfl_down(loc,off);
    if ((tid&63)==0) wsum[tid>>6]=loc;
    __syncthreads();
    if (tid==0) atomicAdd(&acc[1],wsum[0]+wsum[1]+wsum[2]+wsum[3]);
}

__global__ void k_fin(const double* __restrict__ acc, float* __restrict__ out){
    out[0]=(float)(0.5*acc[0]/128.0);
    out[1]=(float)(0.5*acc[1]/6400.0);
}

extern "C" void kernel_launch(void* const* d_in, const int* in_sizes, int n_in,
                              void* d_out, int out_size, void* d_ws, size_t ws_size,
                              hipStream_t stream){
    const float4* reg4=(const float4*)d_in[0];
    const float*  logits=(const float*)d_in[1];
    const float4* anc4=(const float4*)d_in[2];
    const float4* tgt4=(const float4*)d_in[3];
    const int*    labels=(const int*)d_in[4];
    char* ws=(char*)d_ws;
    double*   acc   =(double*)(ws+OFF_ACC);
    float*    t2f   =(float*)(ws+OFF_T2);
    float*    thr   =(float*)(ws+OFF_THR);
    unsigned* gmask =(unsigned*)(ws+OFF_GMASK);
    int*      gcnt  =(int*)(ws+OFF_CNT);
    int*      ccnt  =(int*)(ws+OFF_CCNT);
    unsigned* ghist =(unsigned*)(ws+OFF_HIST);
    float*    candv =(float*)(ws+OFF_CANDV);
    int*      candi =(int*)(ws+OFF_CANDI);
    unsigned* clist =(unsigned*)(ws+OFF_CLIST);

    k_init<<<64,256,0,stream>>>((unsigned*)ws);
    k_lut<<<1,128,0,stream>>>(labels,gmask);
    k_iou<<<dim3(NCH,BB),256,0,stream>>>(anc4,reg4,tgt4,(unsigned*)t2f,ghist,ccnt,clist);
    k_thr<<<NBG,64,0,stream>>>(ghist,thr);
    k_cand<<<dim3(NCH,BB),256,0,stream>>>(anc4,tgt4,thr,gcnt,candv,candi);
    k_select<<<NBG,64,0,stream>>>(anc4,reg4,tgt4,logits,labels,gcnt,candv,candi,acc);
    k_neg<<<4096,256,0,stream>>>((const float4*)logits,acc);
    k_corr<<<256,256,0,stream>>>(anc4,reg4,tgt4,logits,gmask,t2f,ccnt,clist,acc);
    k_fin<<<1,1,0,stream>>>(acc,(float*)d_out);
}

// Round 6
// 341.061 us; speedup vs baseline: 1.4082x; 1.1836x over previous
//
#include <hip/hip_runtime.h>
#include <hip/hip_bf16.h>
#include <math.h>

#define BB 8
#define AA 65536
#define CC 80
#define GG 16
#define KK 50
#define NBG (BB*GG)
#define CAP 2048
#define BINS 64
#define NCH 128
#define CHUNK (AA/NCH)   // 512
#define NIOU (NCH*BB)    // 1024 iou blocks
#define NNEG 4096        // neg blocks

// ws layout (bytes)
#define OFF_ACC   0              // double[2]
#define OFF_T2    16             // float[128]
#define OFF_THR   528            // float[128] (unused now)
#define OFF_GMASK 1040           // uint[B*C]
#define OFF_CNT   3600           // int[128]
#define OFF_CCNT  4112           // int[1]
#define OFF_HIST  4128           // uint[128*64]
#define HEAD_WORDS 9224          // (4128+32768)/4
#define HEAD0 1032               // words zeroed by block 0 (everything below HIST)
#define OFF_CANDV 36896          // float[128*CAP]
#define OFF_CANDI 1085472        // int[128*CAP]
#define OFF_CLIST 2134048        // uint list

__global__ void k_pre(unsigned* __restrict__ w, const int* __restrict__ labels,
                      unsigned* __restrict__ gmask){
    int tid=threadIdx.x;
    if (blockIdx.x==0){
        for (int i=tid; i<HEAD0; i+=256) w[i]=0u;
        __syncthreads();
        if (tid<NBG){
            int b=tid>>4; int c=labels[tid];
            atomicOr(&gmask[b*CC+c], 1u<<(tid&15));
        }
    } else {
        for (unsigned i=HEAD0+(blockIdx.x-1)*256u+tid; i<HEAD_WORDS; i+=63u*256u) w[i]=0u;
    }
}

// fused: blocks [0,NIOU) = per-(b,chunk) anchor pass (decode, t2, 64-bin mqm hist
// with overlap cull, correction emit); blocks [NIOU,NIOU+NNEG) = streaming neg base
__global__ __launch_bounds__(256) void k_iou_neg(const float4* __restrict__ anc4,
        const float4* __restrict__ reg4, const float4* __restrict__ tgt4,
        const float4* __restrict__ lg4,
        unsigned* __restrict__ t2u, unsigned* __restrict__ ghist,
        int* __restrict__ ccnt, unsigned* __restrict__ clist,
        double* __restrict__ acc){
    __shared__ unsigned hist[GG][BINS];
    __shared__ float4 stb[GG];
    __shared__ float sarea[GG];
    __shared__ unsigned st2[GG];
    __shared__ unsigned lbuf[CHUNK];
    __shared__ int lcnt, lbase;
    __shared__ double wsum[4];
    int tid=threadIdx.x;
    int x=blockIdx.x;

    if (x>=NIOU){
        // ---- streaming negative base: sum s^2 * softplus(l) ----
        double loc=0.0;
        const unsigned n4=(unsigned)BB*AA*CC/4u;
        for (unsigned i=(unsigned)(x-NIOU)*256u+tid; i<n4; i+=(unsigned)NNEG*256u){
            float4 v=lg4[i];
            float l[4]={v.x,v.y,v.z,v.w};
            float fs=0.f;
            #pragma unroll
            for (int k=0; k<4; ++k){
                float e=__expf(l[k]);
                float s=e*__builtin_amdgcn_rcpf(1.f+e);
                fs+=s*s*__logf(1.f+e);
            }
            loc+=(double)fs;
        }
        for (int off=32; off; off>>=1) loc+=__shfl_down(loc,off);
        if ((tid&63)==0) wsum[tid>>6]=loc;
        __syncthreads();
        if (tid==0) atomicAdd(&acc[1],wsum[0]+wsum[1]+wsum[2]+wsum[3]);
        return;
    }

    // ---- anchor pass ----
    int blk=x&(NCH-1), b=x>>7;
    for (int j=tid; j<GG*BINS; j+=256) ((unsigned*)hist)[j]=0u;
    if (tid<GG){
        float4 tb=tgt4[b*GG+tid];
        stb[tid]=tb;
        sarea[tid]=(tb.z-tb.x)*(tb.w-tb.y);
        st2[tid]=0u;
    }
    if (tid==0) lcnt=0;
    __syncthreads();
    float mx[GG];
    #pragma unroll
    for (int g=0; g<GG; ++g) mx[g]=0.f;
    int abase=blk*CHUNK+tid;
    for (int it=0; it<CHUNK/256; ++it){
        int a=abase+it*256;
        float4 an=anc4[a];
        float4 br=reg4[b*AA+a];
        float dcx=an.x+br.x*0.1f*an.z;
        float dcy=an.y+br.y*0.1f*an.w;
        float dw=an.z*__expf(br.z*0.2f);
        float dh=an.w*__expf(br.w*0.2f);
        float dx1=dcx-dw*0.5f, dy1=dcy-dh*0.5f, dx2=dcx+dw*0.5f, dy2=dcy+dh*0.5f;
        float dA=dw*dh;
        float ax1=an.x-an.z*0.5f, ay1=an.y-an.w*0.5f;
        float ax2=an.x+an.z*0.5f, ay2=an.y+an.w*0.5f;
        float aA=an.z*an.w;
        bool emit=false;
        #pragma unroll
        for (int g=0; g<GG; ++g){
            float4 tb=stb[g];
            float tA=sarea[g];
            // decoded-box iou (overlap cull)
            {
                float lx=fmaxf(tb.x,dx1), ly=fmaxf(tb.y,dy1);
                float rx=fminf(tb.z,dx2), ry=fminf(tb.w,dy2);
                float w_=rx-lx, h_=ry-ly;
                if (w_>0.f && h_>0.f){
                    float inter=w_*h_;
                    float iou=inter/(tA+dA-inter);
                    mx[g]=fmaxf(mx[g],iou);
                    if (iou>0.5f) emit=true;
                }
            }
            // anchor-box iou -> histogram (overlap cull)
            {
                float lx=fmaxf(tb.x,ax1), ly=fmaxf(tb.y,ay1);
                float rx=fminf(tb.z,ax2), ry=fminf(tb.w,ay2);
                float w_=rx-lx, h_=ry-ly;
                if (w_>0.f && h_>0.f){
                    float inter=w_*h_;
                    float m=inter/(tA+aA-inter);
                    int bin=min(BINS-1,(int)(m*(float)BINS));
                    atomicAdd(&hist[g][bin],1u);
                }
            }
        }
        if (emit){
            int p=atomicAdd(&lcnt,1);
            lbuf[p]=(unsigned)a;
        }
    }
    #pragma unroll
    for (int g=0; g<GG; ++g){
        float v=mx[g];
        for (int off=32; off; off>>=1) v=fmaxf(v,__shfl_down(v,off));
        if ((tid&63)==0) atomicMax(&st2[g],__float_as_uint(v));
    }
    __syncthreads();
    if (tid<GG) atomicMax(&t2u[b*GG+tid],st2[tid]);
    if (tid==0 && lcnt>0) lbase=atomicAdd(ccnt,lcnt);
    __syncthreads();
    for (int j=tid; j<GG*BINS; j+=256){
        unsigned v=((unsigned*)hist)[j];
        if (v) atomicAdd(&ghist[b*GG*BINS+j],v);
    }
    unsigned bb=(unsigned)b<<16;
    for (int j=tid; j<lcnt; j+=256) clist[lbase+j]=bb|lbuf[j];
}

// threshold from histogram (in-block suffix scan) + candidate collection
__global__ __launch_bounds__(256) void k_candthr(const float4* __restrict__ anc4,
        const float4* __restrict__ tgt4, const unsigned* __restrict__ ghist,
        int* __restrict__ gcnt, float* __restrict__ candv, int* __restrict__ candi){
    __shared__ unsigned hist[GG][BINS];
    __shared__ float4 stb[GG];
    __shared__ float sarea[GG];
    __shared__ float sthr[GG];
    int tid=threadIdx.x, blk=blockIdx.x, b=blockIdx.y;
    int lane=tid&63, wv=tid>>6;
    for (int j=tid; j<GG*BINS; j+=256) ((unsigned*)hist)[j]=ghist[b*GG*BINS+j];
    if (tid<GG){
        float4 tb=tgt4[b*GG+tid];
        stb[tid]=tb;
        sarea[tid]=(tb.z-tb.x)*(tb.w-tb.y);
    }
    __syncthreads();
    #pragma unroll
    for (int gg=0; gg<4; ++gg){
        int g=wv*4+gg;
        unsigned v=hist[g][lane];
        #pragma unroll
        for (int off=1; off<64; off<<=1){
            unsigned o=__shfl_down(v,off);
            if (lane+off<64) v+=o;
        }
        unsigned long long mask=__ballot(v>=KK);
        int bs = mask ? (63-__clzll(mask)) : 0;
        if (lane==0) sthr[g]=(float)bs;
    }
    __syncthreads();
    int abase=blk*CHUNK+tid;
    for (int it=0; it<CHUNK/256; ++it){
        int a=abase+it*256;
        float4 an=anc4[a];
        float ax1=an.x-an.z*0.5f, ay1=an.y-an.w*0.5f;
        float ax2=an.x+an.z*0.5f, ay2=an.y+an.w*0.5f;
        float aA=an.z*an.w;
        #pragma unroll
        for (int g=0; g<GG; ++g){
            float4 tb=stb[g];
            float m=0.f;
            {
                float lx=fmaxf(tb.x,ax1), ly=fmaxf(tb.y,ay1);
                float rx=fminf(tb.z,ax2), ry=fminf(tb.w,ay2);
                float w_=rx-lx, h_=ry-ly;
                if (w_>0.f && h_>0.f){
                    float inter=w_*h_;
                    m=inter/(sarea[g]+aA-inter);
                }
            }
            bool push=(m>0.f && m*(float)BINS>=sthr[g]);
            unsigned long long msk=__ballot(push);
            if (msk){
                int bg=b*GG+g;
                int n=__popcll(msk);
                int ldr=__ffsll((long long)msk)-1;
                int base=0;
                if (lane==ldr) base=atomicAdd(&gcnt[bg],n);
                base=__shfl(base,ldr);
                if (push){
                    int p=base+(int)__popcll(msk&((1ull<<lane)-1ull));
                    if (p<CAP){ candv[bg*CAP+p]=m; candi[bg*CAP+p]=a; }
                }
            }
        }
    }
}

// fused: blocks [0,128) top-50 + positive bag loss; blocks [128,384) correction
__global__ __launch_bounds__(256) void k_selcorr(const float4* __restrict__ anc4,
        const float4* __restrict__ reg4, const float4* __restrict__ tgt4,
        const float* __restrict__ logits, const int* __restrict__ labels,
        const int* __restrict__ gcnt, const float* __restrict__ candv,
        const int* __restrict__ candi, const unsigned* __restrict__ gmask,
        const float* __restrict__ t2f, const int* __restrict__ ccnt,
        const unsigned* __restrict__ clist, double* __restrict__ acc){
    __shared__ float cv[CAP];
    __shared__ int ci[CAP];
    __shared__ double wsum[4];
    int tid=threadIdx.x;
    int x=blockIdx.x;

    if (x>=NBG){
        // ---- sparse correction ----
        int n=*ccnt;
        double loc=0.0;
        for (int i=(x-NBG)*256+tid; i<n; i+=256*256){
            unsigned key=clist[i];
            int b=key>>16, a=key&0xffff;
            float4 an=anc4[a];
            float4 br=reg4[b*AA+a];
            float dcx=an.x+br.x*0.1f*an.z;
            float dcy=an.y+br.y*0.1f*an.w;
            float dw=an.z*__expf(br.z*0.2f);
            float dh=an.w*__expf(br.w*0.2f);
            float dx1=dcx-dw*0.5f, dy1=dcy-dh*0.5f, dx2=dcx+dw*0.5f, dy2=dcy+dh*0.5f;
            float dA=dw*dh;
            float obp[GG];
            #pragma unroll
            for (int g=0; g<GG; ++g){
                float4 tb=tgt4[b*GG+g];
                float lx=fmaxf(tb.x,dx1), ly=fmaxf(tb.y,dy1);
                float rx=fminf(tb.z,dx2), ry=fminf(tb.w,dy2);
                float w_=fmaxf(rx-lx,0.f), h_=fmaxf(ry-ly,0.f);
                float inter=w_*h_;
                float tA=(tb.z-tb.x)*(tb.w-tb.y);
                float iou=inter/(tA+dA-inter);
                float d=t2f[b*GG+g]-0.5f;
                float inv=(d>0.f)?1.f/d:0.f;
                obp[g]=fminf(fmaxf((iou-0.5f)*inv,0.f),1.f);
            }
            for (int c=0; c<CC; ++c){
                unsigned m=gmask[b*CC+c];
                if (!m) continue;
                float bp=0.f;
                while (m){ unsigned g=(unsigned)__builtin_ctz(m); m&=m-1u; bp=fmaxf(bp,obp[g]); }
                if (bp<=0.f) continue;
                float lg=logits[((size_t)b*AA+(size_t)a)*CC+c];
                float e=__expf(lg);
                float s=e*__builtin_amdgcn_rcpf(1.f+e);
                float xx=s*(1.f-bp);
                float fx=xx*xx*(-__logf(fmaxf(1.f-xx,1e-12f)));
                float fs=s*s*__logf(1.f+e);
                loc+=(double)(fx-fs);
            }
        }
        for (int off=32; off; off>>=1) loc+=__shfl_down(loc,off);
        if ((tid&63)==0) wsum[tid>>6]=loc;
        __syncthreads();
        if (tid==0) atomicAdd(&acc[1],wsum[0]+wsum[1]+wsum[2]+wsum[3]);
        return;
    }

    // ---- top-50 + positive bag loss (wave 0 after cooperative load) ----
    int bg=x; int b=bg>>4;
    int cnt=gcnt[bg]; if (cnt>CAP) cnt=CAP;
    for (int j=tid; j<cnt; j+=256){ cv[j]=candv[bg*CAP+j]; ci[j]=candi[bg*CAP+j]; }
    __syncthreads();
    if (tid>=64) return;
    int lane=tid;
    int myA=-1;
    for (int k=0; k<KK; ++k){
        float bv=-1e30f; int bi=0x7fffffff; int bj=-1;
        for (int j=lane; j<cnt; j+=64){
            float v=cv[j]; int ii=ci[j];
            if (v>bv || (v==bv && ii<bi)){ bv=v; bi=ii; bj=j; }
        }
        for (int off=32; off; off>>=1){
            float ov=__shfl_down(bv,off); int oi=__shfl_down(bi,off); int oj=__shfl_down(bj,off);
            if (ov>bv || (ov==bv && oi<bi)){ bv=ov; bi=oi; bj=oj; }
        }
        int wj=__shfl(bj,0); int wi=__shfl(bi,0); float wv=__shfl(bv,0);
        if (wv>-1e29f){
            if (lane==(wj&63)) cv[wj]=-1e30f;
            if (lane==k) myA=wi;
        }
    }
    float p=0.f, u=0.f;
    if (lane<KK && myA>=0){
        float4 tb=tgt4[bg];
        int a=myA;
        float4 an=anc4[a];
        int lab=labels[bg];
        float lg=logits[((size_t)b*AA+(size_t)a)*CC+lab];
        float mcp=1.f/(1.f+expf(-lg));
        float gcx=((tb.x+tb.z)*0.5f-an.x)/(0.1f*an.z);
        float gcy=((tb.y+tb.w)*0.5f-an.y)/(0.1f*an.w);
        float gw=logf((tb.z-tb.x)/an.z)/0.2f;
        float gh=logf((tb.w-tb.y)/an.w)/0.2f;
        float4 br=reg4[b*AA+a];
        float v0=gcx-br.x, v1=gcy-br.y, v2=gw-br.z, v3=gh-br.w;
        float s=0.f;
        {float av=fabsf(v0); s+=(av<0.11f)?4.545454545454546f*v0*v0:av-0.055f;}
        {float av=fabsf(v1); s+=(av<0.11f)?4.545454545454546f*v1*v1:av-0.055f;}
        {float av=fabsf(v2); s+=(av<0.11f)?4.545454545454546f*v2*v2:av-0.055f;}
        {float av=fabsf(v3); s+=(av<0.11f)?4.545454545454546f*v3*v3:av-0.055f;}
        float mbp=expf(-(0.75f*s));
        p=mcp*mbp;
        u=1.f/fmaxf(1.f-p,1e-12f);
    }
    float su=u, sp=u*p;
    for (int off=32; off; off>>=1){ su+=__shfl_down(su,off); sp+=__shfl_down(sp,off); }
    if (lane==0) atomicAdd(&acc[0],(double)(-logf(sp/su)));
}

__global__ void k_fin(const double* __restrict__ acc, float* __restrict__ out){
    out[0]=(float)(0.5*acc[0]/128.0);
    out[1]=(float)(0.5*acc[1]/6400.0);
}

extern "C" void kernel_launch(void* const* d_in, const int* in_sizes, int n_in,
                              void* d_out, int out_size, void* d_ws, size_t ws_size,
                              hipStream_t stream){
    const float4* reg4=(const float4*)d_in[0];
    const float*  logits=(const float*)d_in[1];
    const float4* anc4=(const float4*)d_in[2];
    const float4* tgt4=(const float4*)d_in[3];
    const int*    labels=(const int*)d_in[4];
    char* ws=(char*)d_ws;
    double*   acc   =(double*)(ws+OFF_ACC);
    float*    t2f   =(float*)(ws+OFF_T2);
    unsigned* gmask =(unsigned*)(ws+OFF_GMASK);
    int*      gcnt  =(int*)(ws+OFF_CNT);
    int*      ccnt  =(int*)(ws+OFF_CCNT);
    unsigned* ghist =(unsigned*)(ws+OFF_HIST);
    float*    candv =(float*)(ws+OFF_CANDV);
    int*      candi =(int*)(ws+OFF_CANDI);
    unsigned* clist =(unsigned*)(ws+OFF_CLIST);

    k_pre<<<64,256,0,stream>>>((unsigned*)ws,labels,gmask);
    k_iou_neg<<<NIOU+NNEG,256,0,stream>>>(anc4,reg4,tgt4,(const float4*)logits,
                                          (unsigned*)t2f,ghist,ccnt,clist,acc);
    k_candthr<<<dim3(NCH,BB),256,0,stream>>>(anc4,tgt4,ghist,gcnt,candv,candi);
    k_selcorr<<<NBG+256,256,0,stream>>>(anc4,reg4,tgt4,logits,labels,gcnt,candv,candi,
                                        gmask,t2f,ccnt,clist,acc);
    k_fin<<<1,1,0,stream>>>(acc,(float*)d_out);
}